// Round 3
// baseline (516.352 us; speedup 1.0000x reference)
//
#include <hip/hip_runtime.h>
#include <hip/hip_bf16.h>

// Problem constants (match reference)
#define BB 256
#define II 182
#define TT 2000
#define OO 2
#define IHALF 91   // II/2; 91 = 7*13

// Fused kernel, one block per batch b, 1024 threads (16 waves/CU, 4 waves/SIMD).
// i-reduction split in half across the two 512-thread halves to double wave
// count vs the 512-thread version (latency hiding), same coalesced float4 loads.
//   Phase 1: partial curr sums (i-halves) -> combine via LDS -> curr_s
//   Phase 2: serial scan over t (2 lanes, independent chains)
//   Phase 3: cooperative float4 store of out[b][:][:]
__global__ __launch_bounds__(1024) void snn_fused_kernel(const float* __restrict__ in,
                                                         const float* __restrict__ W,
                                                         const float* __restrict__ bias,
                                                         const float* __restrict__ alpha,
                                                         const float* __restrict__ beta,
                                                         float* __restrict__ out) {
    __shared__ float w0[II];
    __shared__ float w1[II];
    __shared__ float part[TT / 4][9];   // upper-half partials, padded to 9 (bank-conflict-free)
    __shared__ float curr_s[OO][TT];    // [o][t], 16 KB
    __shared__ float mem_s[TT * OO];    // [t][o], 16 KB

    const int b = blockIdx.x;
    const int tid = threadIdx.x;

    if (tid < II) {
        w0[tid] = W[tid];       // W[0][i]
        w1[tid] = W[II + tid];  // W[1][i]
    }
    __syncthreads();

    const bool upper = tid >= 512;
    const int g = upper ? tid - 512 : tid;  // t-group (4 consecutive t's)
    const int i0 = upper ? IHALF : 0;

    float4 a0 = {0.f, 0.f, 0.f, 0.f};
    float4 a1 = {0.f, 0.f, 0.f, 0.f};

    if (g < TT / 4) {
        const float4* p = (const float4*)(in + (size_t)b * II * TT) + g + (size_t)i0 * (TT / 4);
#pragma unroll 13
        for (int i = 0; i < IHALF; ++i) {
            const float4 x = p[i * (TT / 4)];
            const float wa = w0[i0 + i];
            const float wb = w1[i0 + i];
            a0.x += x.x * wa; a0.y += x.y * wa; a0.z += x.z * wa; a0.w += x.w * wa;
            a1.x += x.x * wb; a1.y += x.y * wb; a1.z += x.z * wb; a1.w += x.w * wb;
        }
        if (upper) {
            part[g][0] = a0.x; part[g][1] = a0.y; part[g][2] = a0.z; part[g][3] = a0.w;
            part[g][4] = a1.x; part[g][5] = a1.y; part[g][6] = a1.z; part[g][7] = a1.w;
        }
    }
    __syncthreads();

    if (!upper && g < TT / 4) {
        const float b0 = bias[0];
        const float b1 = bias[1];
        const int t = g * 4;
        curr_s[0][t + 0] = a0.x + part[g][0] + b0;
        curr_s[0][t + 1] = a0.y + part[g][1] + b0;
        curr_s[0][t + 2] = a0.z + part[g][2] + b0;
        curr_s[0][t + 3] = a0.w + part[g][3] + b0;
        curr_s[1][t + 0] = a1.x + part[g][4] + b1;
        curr_s[1][t + 1] = a1.y + part[g][5] + b1;
        curr_s[1][t + 2] = a1.z + part[g][6] + b1;
        curr_s[1][t + 3] = a1.w + part[g][7] + b1;
    }
    __syncthreads();

    // ---- Phase 2: serial scan, one lane per o ----
    if (tid < OO) {
        const int o = tid;
        const float a  = fminf(fmaxf(alpha[o], 0.f), 1.f);
        const float bt = fminf(fmaxf(beta[o],  0.f), 1.f);
        const float4* c4 = (const float4*)curr_s[o];
        float syn = 0.f, mem = 0.f;
        for (int t4 = 0; t4 < TT / 4; ++t4) {
            const float4 x = c4[t4];
            const int t = t4 * 4;
            syn = a * syn + x.x; mem = bt * mem + syn; mem_s[(t + 0) * OO + o] = mem;
            syn = a * syn + x.y; mem = bt * mem + syn; mem_s[(t + 1) * OO + o] = mem;
            syn = a * syn + x.z; mem = bt * mem + syn; mem_s[(t + 2) * OO + o] = mem;
            syn = a * syn + x.w; mem = bt * mem + syn; mem_s[(t + 3) * OO + o] = mem;
        }
    }
    __syncthreads();

    // ---- Phase 3: coalesced store of out[b][t][o] (4000 floats = 1000 float4) ----
    float4* o4 = (float4*)(out + (size_t)b * TT * OO);
    const float4* m4 = (const float4*)mem_s;
    if (tid < TT * OO / 4) {
        o4[tid] = m4[tid];
    }
}

extern "C" void kernel_launch(void* const* d_in, const int* in_sizes, int n_in,
                              void* d_out, int out_size, void* d_ws, size_t ws_size,
                              hipStream_t stream) {
    const float* inputs = (const float*)d_in[0];  // [B, I, T]
    const float* W      = (const float*)d_in[1];  // [O, I]
    const float* bias   = (const float*)d_in[2];  // [O]
    const float* alpha  = (const float*)d_in[3];  // [O]
    const float* beta   = (const float*)d_in[4];  // [O]
    float* out = (float*)d_out;                   // [B, T, O]

    snn_fused_kernel<<<BB, 1024, 0, stream>>>(inputs, W, bias, alpha, beta, out);
}